// Round 10
// baseline (53.078 us; speedup 1.0000x reference)
//
#include <hip/hip_runtime.h>

#define R     8
#define K     17               // 2*r+1
#define W     512
#define H     512
#define ROWS  16               // output rows per tile
#define LDSW  532              // 8 halo + 512 + 8 halo + 4 pad floats
#define TILES 4                // strips per block (1/8 plane)

typedef float f32x4 __attribute__((ext_vector_type(4)));

// Joint-liveness pin: holds all 16 values live at this point so the 16 loads
// must be issued as a cluster BEFORE this program point (can't be sunk below).
__device__ __forceinline__ void pin16(float* r) {
    asm volatile("" : "+v"(r[0]), "+v"(r[1]), "+v"(r[2]),  "+v"(r[3]),
                      "+v"(r[4]), "+v"(r[5]), "+v"(r[6]),  "+v"(r[7]),
                      "+v"(r[8]), "+v"(r[9]), "+v"(r[10]), "+v"(r[11]),
                      "+v"(r[12]),"+v"(r[13]),"+v"(r[14]), "+v"(r[15]));
}

// Load 16 consecutive rows of one column (zeros outside the image).
__device__ __forceinline__ void load16(const float* __restrict__ src,
                                       int row0, int col, float* d) {
    #pragma unroll
    for (int j = 0; j < 16; ++j) {
        const int gy = row0 + j;
        float v = 0.0f;
        if ((unsigned)gy < (unsigned)H) v = src[gy * W + col];
        d[j] = v;
    }
    pin16(d);
}

// Vertical sliding sums: hi = rows y0-8..y0+7, lo = rows y0+8..y0+23.
__device__ __forceinline__ void vpass(const float* hi, const float* lo,
                                      int col, float (*s_v)[LDSW], float inv_k) {
    float s = 0.0f;
    #pragma unroll
    for (int j = 0; j < 16; ++j) s += hi[j];
    s += lo[0];                                   // 17 rows: y0-8..y0+8
    s_v[0][8 + col] = s * inv_k;
    #pragma unroll
    for (int i = 1; i < 16; ++i) {
        s += lo[i] - hi[i - 1];
        s_v[i][8 + col] = s * inv_k;
    }
}

// Horizontal pass + nt stores.
__device__ __forceinline__ void hpass_store(const float (*s_v)[LDSW],
                                            float* __restrict__ dst,
                                            int y0, int tid, float inv_k) {
    #pragma unroll
    for (int itq = 0; itq < 4; ++itq) {
        const int q  = tid + itq * 512;
        const int y  = q >> 7;                 // 0..15
        const int x4 = (q & 127) * 4;          // 0..508
        const float* vrow = &s_v[y][8];

        const float4 f0 = *reinterpret_cast<const float4*>(vrow + x4 - 8);
        const float4 f1 = *reinterpret_cast<const float4*>(vrow + x4 - 4);
        const float4 f2 = *reinterpret_cast<const float4*>(vrow + x4);
        const float4 f3 = *reinterpret_cast<const float4*>(vrow + x4 + 4);
        const float4 f4 = *reinterpret_cast<const float4*>(vrow + x4 + 8);

        float o0 = f0.x + f0.y + f0.z + f0.w
                 + f1.x + f1.y + f1.z + f1.w
                 + f2.x + f2.y + f2.z + f2.w
                 + f3.x + f3.y + f3.z + f3.w
                 + f4.x;
        const float o1 = o0 - f0.x + f4.y;
        const float o2 = o1 - f0.y + f4.z;
        const float o3 = o2 - f0.z + f4.w;

        f32x4 o;
        o.x = o0 * inv_k; o.y = o1 * inv_k; o.z = o2 * inv_k; o.w = o3 * inv_k;
        __builtin_nontemporal_store(o,
            reinterpret_cast<f32x4*>(&dst[(y0 + y) * W + x4]));
    }
}

// Pipelined fused box filter: each block marches down 4 strips of one plane.
// Register ping-pong (A/B) rotates the vertical window: 16 new rows/iter,
// issued BEFORE pass2+barriers so HBM runs under the LDS/store phase.
// 1024 blocks -> 4 blocks/CU (LDS 4x34KB=136KB, 32/32 wave slots).
__global__ __launch_bounds__(512, 8)
void box_pipe4(const float* __restrict__ x, float* __restrict__ out) {
    const int bid   = blockIdx.x;              // 0..1023
    const int plane = bid >> 3;                // 128 planes
    const int s0    = (bid & 7) * TILES;       // first strip: 0,4,...,28
    const float* __restrict__ src = x   + (size_t)plane * (W * H);
    float* __restrict__       dst = out + (size_t)plane * (W * H);

    __shared__ __align__(16) float s_v[ROWS][LDSW];   // 34,048 B

    const int tid = threadIdx.x;
    const int col = tid;                       // 0..511
    const float inv_k = 1.0f / (float)K;

    // zero halo cols once (visible to pass2 via the in-loop barrier)
    if (tid < 64) {
        const int row = tid >> 2;
        const int q   = tid & 3;
        const int c4  = (q == 0) ? 0 : (q == 1) ? 4 : (q == 2) ? 520 : 524;
        *reinterpret_cast<float4*>(&s_v[row][c4]) = make_float4(0.f, 0.f, 0.f, 0.f);
    }

    float A[16], B[16];
    const int ybase = s0 * ROWS;

    // prologue: A = rows ybase-8..ybase+7 (hi), B = rows ybase+8..ybase+23 (lo)
    load16(src, ybase - R, col, A);
    load16(src, ybase + R, col, B);

    for (int it = 0; it < TILES / 2; ++it) {
        // ---- even tile: hi=A, lo=B; next rows -> A ----
        {
            const int y0 = (s0 + 2 * it) * ROWS;
            vpass(A, B, col, s_v, inv_k);
            load16(src, y0 + 24, col, A);      // next tile's lo, in flight below
            __syncthreads();
            hpass_store(s_v, dst, y0, tid, inv_k);
            __syncthreads();
        }
        // ---- odd tile: hi=B, lo=A; next rows -> B ----
        {
            const int y0 = (s0 + 2 * it + 1) * ROWS;
            vpass(B, A, col, s_v, inv_k);
            if (it < TILES / 2 - 1)
                load16(src, y0 + 24, col, B);
            __syncthreads();
            hpass_store(s_v, dst, y0, tid, inv_k);
            __syncthreads();
        }
    }
}

extern "C" void kernel_launch(void* const* d_in, const int* in_sizes, int n_in,
                              void* d_out, int out_size, void* d_ws, size_t ws_size,
                              hipStream_t stream) {
    const float* x = (const float*)d_in[0];
    float* out = (float*)d_out;
    // x: (8, 16, 512, 512) fp32; r = 8 fixed
    box_pipe4<<<dim3(1024), dim3(512), 0, stream>>>(x, out);
}

// Round 11
// 47.867 us; speedup vs baseline: 1.1089x; 1.1089x over previous
//
#include <hip/hip_runtime.h>

#define R     8
#define K     17               // 2*r+1
#define W     512
#define H     512
#define ROWS  16               // output rows per tile
#define LDSW  532              // 8 halo + 512 + 8 halo + 4 pad floats
#define TILES 4                // strips per block (1/8 plane)

typedef float f32x4 __attribute__((ext_vector_type(4)));

// Joint-liveness pin: holds all 16 values live at this point so the 16 loads
// must be issued as a cluster BEFORE this program point (can't be sunk below).
__device__ __forceinline__ void pin16(float* r) {
    asm volatile("" : "+v"(r[0]), "+v"(r[1]), "+v"(r[2]),  "+v"(r[3]),
                      "+v"(r[4]), "+v"(r[5]), "+v"(r[6]),  "+v"(r[7]),
                      "+v"(r[8]), "+v"(r[9]), "+v"(r[10]), "+v"(r[11]),
                      "+v"(r[12]),"+v"(r[13]),"+v"(r[14]), "+v"(r[15]));
}

// Load 16 consecutive rows of one column (zeros outside the image).
__device__ __forceinline__ void load16(const float* __restrict__ src,
                                       int row0, int col, float* d) {
    #pragma unroll
    for (int j = 0; j < 16; ++j) {
        const int gy = row0 + j;
        float v = 0.0f;
        if ((unsigned)gy < (unsigned)H) v = src[gy * W + col];
        d[j] = v;
    }
    pin16(d);
}

// Vertical sliding sums: hi = rows y0-8..y0+7, lo = rows y0+8..y0+23.
__device__ __forceinline__ void vpass(const float* hi, const float* lo,
                                      int col, float (*s_v)[LDSW], float inv_k) {
    float s = 0.0f;
    #pragma unroll
    for (int j = 0; j < 16; ++j) s += hi[j];
    s += lo[0];                                   // 17 rows: y0-8..y0+8
    s_v[0][8 + col] = s * inv_k;
    #pragma unroll
    for (int i = 1; i < 16; ++i) {
        s += lo[i] - hi[i - 1];
        s_v[i][8 + col] = s * inv_k;
    }
}

// Horizontal pass + nt stores.
__device__ __forceinline__ void hpass_store(const float (*s_v)[LDSW],
                                            float* __restrict__ dst,
                                            int y0, int tid, float inv_k) {
    #pragma unroll
    for (int itq = 0; itq < 4; ++itq) {
        const int q  = tid + itq * 512;
        const int y  = q >> 7;                 // 0..15
        const int x4 = (q & 127) * 4;          // 0..508
        const float* vrow = &s_v[y][8];

        const float4 f0 = *reinterpret_cast<const float4*>(vrow + x4 - 8);
        const float4 f1 = *reinterpret_cast<const float4*>(vrow + x4 - 4);
        const float4 f2 = *reinterpret_cast<const float4*>(vrow + x4);
        const float4 f3 = *reinterpret_cast<const float4*>(vrow + x4 + 4);
        const float4 f4 = *reinterpret_cast<const float4*>(vrow + x4 + 8);

        float o0 = f0.x + f0.y + f0.z + f0.w
                 + f1.x + f1.y + f1.z + f1.w
                 + f2.x + f2.y + f2.z + f2.w
                 + f3.x + f3.y + f3.z + f3.w
                 + f4.x;
        const float o1 = o0 - f0.x + f4.y;
        const float o2 = o1 - f0.y + f4.z;
        const float o3 = o2 - f0.z + f4.w;

        f32x4 o;
        o.x = o0 * inv_k; o.y = o1 * inv_k; o.z = o2 * inv_k; o.w = o3 * inv_k;
        __builtin_nontemporal_store(o,
            reinterpret_cast<f32x4*>(&dst[(y0 + y) * W + x4]));
    }
}

// Pipelined fused box filter: each block marches down 4 strips of one plane.
// Register ping-pong (A/B) rotates the vertical window: 16 new rows/iter,
// issued BEFORE pass2+barriers so HBM runs under the LDS/store phase.
// 1024 blocks -> 4 blocks/CU (LDS 4x34KB=136KB, 32/32 wave slots).
// NOTE: launch_bounds min-waves MUST stay 4 (VGPR cap 128): R10's (512,8)
// capped VGPR at 32 -> A/B spilled to scratch (WRITE_SIZE +13MB, -9% perf).
__global__ __launch_bounds__(512, 4)
void box_pipe4b(const float* __restrict__ x, float* __restrict__ out) {
    const int bid   = blockIdx.x;              // 0..1023
    const int plane = bid >> 3;                // 128 planes
    const int s0    = (bid & 7) * TILES;       // first strip: 0,4,...,28
    const float* __restrict__ src = x   + (size_t)plane * (W * H);
    float* __restrict__       dst = out + (size_t)plane * (W * H);

    __shared__ __align__(16) float s_v[ROWS][LDSW];   // 34,048 B

    const int tid = threadIdx.x;
    const int col = tid;                       // 0..511
    const float inv_k = 1.0f / (float)K;

    // zero halo cols once (visible to pass2 via the in-loop barrier)
    if (tid < 64) {
        const int row = tid >> 2;
        const int q   = tid & 3;
        const int c4  = (q == 0) ? 0 : (q == 1) ? 4 : (q == 2) ? 520 : 524;
        *reinterpret_cast<float4*>(&s_v[row][c4]) = make_float4(0.f, 0.f, 0.f, 0.f);
    }

    float A[16], B[16];
    const int ybase = s0 * ROWS;

    // prologue: A = rows ybase-8..ybase+7 (hi), B = rows ybase+8..ybase+23 (lo)
    load16(src, ybase - R, col, A);
    load16(src, ybase + R, col, B);

    for (int it = 0; it < TILES / 2; ++it) {
        // ---- even tile: hi=A, lo=B; next rows -> A ----
        {
            const int y0 = (s0 + 2 * it) * ROWS;
            vpass(A, B, col, s_v, inv_k);
            load16(src, y0 + 24, col, A);      // next tile's lo, in flight below
            __syncthreads();
            hpass_store(s_v, dst, y0, tid, inv_k);
            __syncthreads();
        }
        // ---- odd tile: hi=B, lo=A; next rows -> B ----
        {
            const int y0 = (s0 + 2 * it + 1) * ROWS;
            vpass(B, A, col, s_v, inv_k);
            if (it < TILES / 2 - 1)
                load16(src, y0 + 24, col, B);
            __syncthreads();
            hpass_store(s_v, dst, y0, tid, inv_k);
            __syncthreads();
        }
    }
}

extern "C" void kernel_launch(void* const* d_in, const int* in_sizes, int n_in,
                              void* d_out, int out_size, void* d_ws, size_t ws_size,
                              hipStream_t stream) {
    const float* x = (const float*)d_in[0];
    float* out = (float*)d_out;
    // x: (8, 16, 512, 512) fp32; r = 8 fixed
    box_pipe4b<<<dim3(1024), dim3(512), 0, stream>>>(x, out);
}